// Round 1
// 999.040 us; speedup vs baseline: 1.0767x; 1.0767x over previous
//
#include <hip/hip_runtime.h>

#define N_NODES 12288
#define IN_DIM_ 256
#define HID_ 64
#define E_EDGES 393216
#define TOT_EDGES (E_EDGES + N_NODES)  // 405504

typedef __attribute__((ext_vector_type(8))) short bf16x8;
typedef __attribute__((ext_vector_type(16))) float f32x16;

__device__ inline unsigned short f2bf_rne(float f) {
  unsigned int u = __float_as_uint(f);
  unsigned int r = u + 0x7fffu + ((u >> 16) & 1u);
  return (unsigned short)(r >> 16);
}
__device__ inline float bf2f(unsigned short h) {
  return __uint_as_float(((unsigned int)h) << 16);
}

// ---------------------------------------------------------------- graph build

__global__ __launch_bounds__(256) void k_init(const float* __restrict__ x,
                                              int* __restrict__ deg,
                                              float* __restrict__ coef) {
  int i = blockIdx.x * 256 + threadIdx.x;
  if (i < N_NODES) {
    deg[i] = 1;  // self loop
    coef[i] = 1.0f - 2.0f * x[(size_t)i * IN_DIM_];
  }
}

__global__ __launch_bounds__(256) void k_count(const int* __restrict__ dst,
                                               int* __restrict__ deg) {
  int e = blockIdx.x * 256 + threadIdx.x;
  if (e < E_EDGES) atomicAdd(&deg[dst[e]], 1);
}

__global__ __launch_bounds__(1024) void k_scan(const int* __restrict__ deg,
                                               int* __restrict__ rowptr,
                                               int* __restrict__ cursor,
                                               float* __restrict__ dinv) {
  __shared__ int sh[1024];
  const int t = threadIdx.x;
  int loc[12];
  int s = 0;
#pragma unroll
  for (int i = 0; i < 12; i++) {
    int d = deg[t * 12 + i];
    dinv[t * 12 + i] = 1.0f / sqrtf((float)d);
    loc[i] = s;
    s += d;
  }
  sh[t] = s;
  __syncthreads();
  for (int off = 1; off < 1024; off <<= 1) {
    int v = (t >= off) ? sh[t - off] : 0;
    __syncthreads();
    sh[t] += v;
    __syncthreads();
  }
  int base = sh[t] - s;  // exclusive
#pragma unroll
  for (int i = 0; i < 12; i++) {
    int v = base + loc[i];
    rowptr[t * 12 + i] = v;
    cursor[t * 12 + i] = v;
  }
  if (t == 1023) rowptr[N_NODES] = sh[1023];
}

__global__ __launch_bounds__(256) void k_fill(const int* __restrict__ src,
                                              const int* __restrict__ dst,
                                              const float* __restrict__ dinv,
                                              int* __restrict__ cursor,
                                              int* __restrict__ col,
                                              float* __restrict__ wgt) {
  int e = blockIdx.x * 256 + threadIdx.x;
  if (e < E_EDGES) {
    int s = src[e], d = dst[e];
    int pos = atomicAdd(&cursor[d], 1);
    col[pos] = s;
    wgt[pos] = dinv[s] * dinv[d];
  } else if (e < TOT_EDGES) {
    int i = e - E_EDGES;
    int pos = atomicAdd(&cursor[i], 1);
    col[pos] = i;
    float di = dinv[i];
    wgt[pos] = di * di;
  }
}

// ---------------------------------------------------------------- aggregation
// One wave per node, MLP-8 (8 independent gathers in flight; avg degree ~33 ->
// 4 full iterations, halving col-load->gather dependent rounds vs unroll-4).

template <bool BIAS, bool RELU, bool SPLIT>
__global__ __launch_bounds__(256) void k_agg64(const float* __restrict__ in,
                                               const int* __restrict__ rowptr,
                                               const int* __restrict__ col,
                                               const float* __restrict__ wgt,
                                               const float* __restrict__ bias,
                                               float* __restrict__ out,
                                               float* __restrict__ out2) {
  const int lane = threadIdx.x & 63;
  int node = blockIdx.x * 4 + (threadIdx.x >> 6);
  node = __builtin_amdgcn_readfirstlane(node);
  const int start = rowptr[node];
  const int end = rowptr[node + 1];
  float a0 = 0.0f, a1 = 0.0f, a2 = 0.0f, a3 = 0.0f;
  int e = start;
  for (; e + 8 <= end; e += 8) {
    int c0 = col[e + 0], c1 = col[e + 1], c2 = col[e + 2], c3 = col[e + 3];
    int c4 = col[e + 4], c5 = col[e + 5], c6 = col[e + 6], c7 = col[e + 7];
    float w0 = wgt[e + 0], w1 = wgt[e + 1], w2 = wgt[e + 2], w3 = wgt[e + 3];
    float w4 = wgt[e + 4], w5 = wgt[e + 5], w6 = wgt[e + 6], w7 = wgt[e + 7];
    float v0 = in[(size_t)c0 * 64 + lane];
    float v1 = in[(size_t)c1 * 64 + lane];
    float v2 = in[(size_t)c2 * 64 + lane];
    float v3 = in[(size_t)c3 * 64 + lane];
    float v4 = in[(size_t)c4 * 64 + lane];
    float v5 = in[(size_t)c5 * 64 + lane];
    float v6 = in[(size_t)c6 * 64 + lane];
    float v7 = in[(size_t)c7 * 64 + lane];
    a0 = fmaf(w0, v0, a0);
    a1 = fmaf(w1, v1, a1);
    a2 = fmaf(w2, v2, a2);
    a3 = fmaf(w3, v3, a3);
    a0 = fmaf(w4, v4, a0);
    a1 = fmaf(w5, v5, a1);
    a2 = fmaf(w6, v6, a2);
    a3 = fmaf(w7, v7, a3);
  }
  for (; e < end; ++e) {
    int c = col[e];
    a0 = fmaf(wgt[e], in[(size_t)c * 64 + lane], a0);
  }
  float acc = (a0 + a1) + (a2 + a3);
  if (BIAS) acc += bias[lane];
  if (RELU) acc = fmaxf(acc, 0.0f);
  if (SPLIT) {
    if (lane < 32)
      out[(size_t)node * 32 + lane] = acc;
    else
      out2[(size_t)node * 32 + (lane - 32)] = acc;
  } else {
    out[(size_t)node * 64 + lane] = acc;
  }
}

// Batched encoder agg: slice 0 = h1 (plain), slice 1 = h1cf (rank-1 fused).
// wr=0 for slice 0 makes fmaf(coef, wr, v) an exact identity.
__global__ __launch_bounds__(256) void k_agg64_enc(
    const float* __restrict__ in, const int* __restrict__ rowptr,
    const int* __restrict__ col, const float* __restrict__ wgt,
    const float* __restrict__ bias, const float* __restrict__ coef,
    const float* __restrict__ wrow, float* __restrict__ out0,
    float* __restrict__ out1) {
  const int lane = threadIdx.x & 63;
  int node = blockIdx.x * 4 + (threadIdx.x >> 6);
  node = __builtin_amdgcn_readfirstlane(node);
  const int slice = blockIdx.y;
  const float wr = slice ? wrow[lane] : 0.0f;
  const int start = rowptr[node];
  const int end = rowptr[node + 1];
  float a0 = 0.0f, a1 = 0.0f, a2 = 0.0f, a3 = 0.0f;
  int e = start;
  for (; e + 8 <= end; e += 8) {
    int c0 = col[e + 0], c1 = col[e + 1], c2 = col[e + 2], c3 = col[e + 3];
    int c4 = col[e + 4], c5 = col[e + 5], c6 = col[e + 6], c7 = col[e + 7];
    float w0 = wgt[e + 0], w1 = wgt[e + 1], w2 = wgt[e + 2], w3 = wgt[e + 3];
    float w4 = wgt[e + 4], w5 = wgt[e + 5], w6 = wgt[e + 6], w7 = wgt[e + 7];
    float v0 = in[(size_t)c0 * 64 + lane];
    float v1 = in[(size_t)c1 * 64 + lane];
    float v2 = in[(size_t)c2 * 64 + lane];
    float v3 = in[(size_t)c3 * 64 + lane];
    float v4 = in[(size_t)c4 * 64 + lane];
    float v5 = in[(size_t)c5 * 64 + lane];
    float v6 = in[(size_t)c6 * 64 + lane];
    float v7 = in[(size_t)c7 * 64 + lane];
    v0 = fmaf(coef[c0], wr, v0);
    v1 = fmaf(coef[c1], wr, v1);
    v2 = fmaf(coef[c2], wr, v2);
    v3 = fmaf(coef[c3], wr, v3);
    v4 = fmaf(coef[c4], wr, v4);
    v5 = fmaf(coef[c5], wr, v5);
    v6 = fmaf(coef[c6], wr, v6);
    v7 = fmaf(coef[c7], wr, v7);
    a0 = fmaf(w0, v0, a0);
    a1 = fmaf(w1, v1, a1);
    a2 = fmaf(w2, v2, a2);
    a3 = fmaf(w3, v3, a3);
    a0 = fmaf(w4, v4, a0);
    a1 = fmaf(w5, v5, a1);
    a2 = fmaf(w6, v6, a2);
    a3 = fmaf(w7, v7, a3);
  }
  for (; e < end; ++e) {
    int c = col[e];
    float v = in[(size_t)c * 64 + lane];
    v = fmaf(coef[c], wr, v);
    a0 = fmaf(wgt[e], v, a0);
  }
  float acc = (a0 + a1) + (a2 + a3) + bias[lane];
  acc = fmaxf(acc, 0.0f);
  (slice ? out1 : out0)[(size_t)node * 64 + lane] = acc;
}

// Batched plain agg64 over three independent decoder chains (blockIdx.y).
__global__ __launch_bounds__(256) void k_agg64_dec3(
    const float* __restrict__ in0, const float* __restrict__ in1,
    const float* __restrict__ in2, const int* __restrict__ rowptr,
    const int* __restrict__ col, const float* __restrict__ wgt,
    float* __restrict__ out0, float* __restrict__ out1,
    float* __restrict__ out2) {
  const int lane = threadIdx.x & 63;
  int node = blockIdx.x * 4 + (threadIdx.x >> 6);
  node = __builtin_amdgcn_readfirstlane(node);
  const int slice = blockIdx.y;
  const float* __restrict__ in = slice == 0 ? in0 : (slice == 1 ? in1 : in2);
  float* __restrict__ out = slice == 0 ? out0 : (slice == 1 ? out1 : out2);
  const int start = rowptr[node];
  const int end = rowptr[node + 1];
  float a0 = 0.0f, a1 = 0.0f, a2 = 0.0f, a3 = 0.0f;
  int e = start;
  for (; e + 8 <= end; e += 8) {
    int c0 = col[e + 0], c1 = col[e + 1], c2 = col[e + 2], c3 = col[e + 3];
    int c4 = col[e + 4], c5 = col[e + 5], c6 = col[e + 6], c7 = col[e + 7];
    float w0 = wgt[e + 0], w1 = wgt[e + 1], w2 = wgt[e + 2], w3 = wgt[e + 3];
    float w4 = wgt[e + 4], w5 = wgt[e + 5], w6 = wgt[e + 6], w7 = wgt[e + 7];
    float v0 = in[(size_t)c0 * 64 + lane];
    float v1 = in[(size_t)c1 * 64 + lane];
    float v2 = in[(size_t)c2 * 64 + lane];
    float v3 = in[(size_t)c3 * 64 + lane];
    float v4 = in[(size_t)c4 * 64 + lane];
    float v5 = in[(size_t)c5 * 64 + lane];
    float v6 = in[(size_t)c6 * 64 + lane];
    float v7 = in[(size_t)c7 * 64 + lane];
    a0 = fmaf(w0, v0, a0);
    a1 = fmaf(w1, v1, a1);
    a2 = fmaf(w2, v2, a2);
    a3 = fmaf(w3, v3, a3);
    a0 = fmaf(w4, v4, a0);
    a1 = fmaf(w5, v5, a1);
    a2 = fmaf(w6, v6, a2);
    a3 = fmaf(w7, v7, a3);
  }
  for (; e < end; ++e) {
    int c = col[e];
    a0 = fmaf(wgt[e], in[(size_t)c * 64 + lane], a0);
  }
  float acc = (a0 + a1) + (a2 + a3);
  out[(size_t)node * 64 + lane] = acc;
}

template <bool BIAS>
__global__ __launch_bounds__(256) void k_agg32(const float* __restrict__ in,
                                               const int* __restrict__ rowptr,
                                               const int* __restrict__ col,
                                               const float* __restrict__ wgt,
                                               const float* __restrict__ bias,
                                               float* __restrict__ out) {
  const int lane = threadIdx.x & 31;
  const int node = blockIdx.x * 8 + (threadIdx.x >> 5);
  const int start = rowptr[node];
  const int end = rowptr[node + 1];
  float a0 = 0.0f, a1 = 0.0f, a2 = 0.0f, a3 = 0.0f;
  int e = start;
  for (; e + 8 <= end; e += 8) {
    int c0 = col[e + 0], c1 = col[e + 1], c2 = col[e + 2], c3 = col[e + 3];
    int c4 = col[e + 4], c5 = col[e + 5], c6 = col[e + 6], c7 = col[e + 7];
    float w0 = wgt[e + 0], w1 = wgt[e + 1], w2 = wgt[e + 2], w3 = wgt[e + 3];
    float w4 = wgt[e + 4], w5 = wgt[e + 5], w6 = wgt[e + 6], w7 = wgt[e + 7];
    a0 = fmaf(w0, in[(size_t)c0 * 32 + lane], a0);
    a1 = fmaf(w1, in[(size_t)c1 * 32 + lane], a1);
    a2 = fmaf(w2, in[(size_t)c2 * 32 + lane], a2);
    a3 = fmaf(w3, in[(size_t)c3 * 32 + lane], a3);
    a0 = fmaf(w4, in[(size_t)c4 * 32 + lane], a0);
    a1 = fmaf(w5, in[(size_t)c5 * 32 + lane], a1);
    a2 = fmaf(w6, in[(size_t)c6 * 32 + lane], a2);
    a3 = fmaf(w7, in[(size_t)c7 * 32 + lane], a3);
  }
  for (; e < end; ++e) a0 = fmaf(wgt[e], in[(size_t)col[e] * 32 + lane], a0);
  float acc = (a0 + a1) + (a2 + a3);
  if (BIAS) acc += bias[lane];
  out[(size_t)node * 32 + lane] = acc;
}

// Batched agg32 for gs / gscf / gns (all bias-free).
__global__ __launch_bounds__(256) void k_agg32_b3(
    const float* __restrict__ in0, const float* __restrict__ in1,
    const float* __restrict__ in2, const int* __restrict__ rowptr,
    const int* __restrict__ col, const float* __restrict__ wgt,
    float* __restrict__ out0, float* __restrict__ out1,
    float* __restrict__ out2) {
  const int lane = threadIdx.x & 31;
  const int node = blockIdx.x * 8 + (threadIdx.x >> 5);
  const int slice = blockIdx.y;
  const float* __restrict__ in = slice == 0 ? in0 : (slice == 1 ? in1 : in2);
  float* __restrict__ out = slice == 0 ? out0 : (slice == 1 ? out1 : out2);
  const int start = rowptr[node];
  const int end = rowptr[node + 1];
  float a0 = 0.0f, a1 = 0.0f, a2 = 0.0f, a3 = 0.0f;
  int e = start;
  for (; e + 8 <= end; e += 8) {
    int c0 = col[e + 0], c1 = col[e + 1], c2 = col[e + 2], c3 = col[e + 3];
    int c4 = col[e + 4], c5 = col[e + 5], c6 = col[e + 6], c7 = col[e + 7];
    float w0 = wgt[e + 0], w1 = wgt[e + 1], w2 = wgt[e + 2], w3 = wgt[e + 3];
    float w4 = wgt[e + 4], w5 = wgt[e + 5], w6 = wgt[e + 6], w7 = wgt[e + 7];
    a0 = fmaf(w0, in[(size_t)c0 * 32 + lane], a0);
    a1 = fmaf(w1, in[(size_t)c1 * 32 + lane], a1);
    a2 = fmaf(w2, in[(size_t)c2 * 32 + lane], a2);
    a3 = fmaf(w3, in[(size_t)c3 * 32 + lane], a3);
    a0 = fmaf(w4, in[(size_t)c4 * 32 + lane], a0);
    a1 = fmaf(w5, in[(size_t)c5 * 32 + lane], a1);
    a2 = fmaf(w6, in[(size_t)c6 * 32 + lane], a2);
    a3 = fmaf(w7, in[(size_t)c7 * 32 + lane], a3);
  }
  for (; e < end; ++e) a0 = fmaf(wgt[e], in[(size_t)col[e] * 32 + lane], a0);
  out[(size_t)node * 32 + lane] = (a0 + a1) + (a2 + a3);
}

// ---------------------------------------------------------------- small GEMM

template <int K, int NF, int LDW, int RPT, bool BIAS, bool RELU>
__global__ __launch_bounds__(256) void k_gemm(const float* __restrict__ A,
                                              const float* __restrict__ W,
                                              const float* __restrict__ bias,
                                              float* __restrict__ C) {
  __shared__ float Ws[K * NF];
  for (int i = threadIdx.x; i < K * NF; i += 256) {
    int k = i / NF, c2 = i % NF;
    Ws[i] = W[k * LDW + c2];
  }
  __syncthreads();
  constexpr int G = 256 / NF;
  const int c = threadIdx.x % NF;
  const int rg = threadIdx.x / NF;
  const int r0 = blockIdx.x * (G * RPT) + rg * RPT;
  float acc[RPT];
#pragma unroll
  for (int i = 0; i < RPT; i++) acc[i] = 0.0f;
#pragma unroll 4
  for (int k = 0; k < K; ++k) {
    float wv = Ws[k * NF + c];
#pragma unroll
    for (int i = 0; i < RPT; i++)
      acc[i] = fmaf(A[(size_t)(r0 + i) * K + k], wv, acc[i]);
  }
  float b = BIAS ? bias[c] : 0.0f;
#pragma unroll
  for (int i = 0; i < RPT; i++) {
    float v = acc[i] + b;
    if (RELU) v = fmaxf(v, 0.0f);
    C[(size_t)(r0 + i) * NF + c] = v;
  }
}

// Batched encoder stage-2: slice 0: HWe2 = h1 @ eW2 (full 64 cols);
// slice 1: t32 = h1cf @ eW2[:, :32] (writes only c<32, stride 32).
__global__ __launch_bounds__(256) void k_gemm_enc2(
    const float* __restrict__ A0, const float* __restrict__ A1,
    const float* __restrict__ W, float* __restrict__ C0,
    float* __restrict__ C1) {
  __shared__ float Ws[64 * 64];
  const int slice = blockIdx.y;
  const float* __restrict__ A = slice ? A1 : A0;
  for (int i = threadIdx.x; i < 64 * 64; i += 256) Ws[i] = W[i];
  __syncthreads();
  const int c = threadIdx.x & 63;
  const int rg = threadIdx.x >> 6;
  const int r0 = blockIdx.x * 32 + rg * 8;
  float acc[8];
#pragma unroll
  for (int i = 0; i < 8; i++) acc[i] = 0.0f;
#pragma unroll 4
  for (int k = 0; k < 64; ++k) {
    float wv = Ws[k * 64 + c];
#pragma unroll
    for (int i = 0; i < 8; i++)
      acc[i] = fmaf(A[(size_t)(r0 + i) * 64 + k], wv, acc[i]);
  }
  if (slice == 0) {
#pragma unroll
    for (int i = 0; i < 8; i++) C0[(size_t)(r0 + i) * 64 + c] = acc[i];
  } else if (c < 32) {
#pragma unroll
    for (int i = 0; i < 8; i++) C1[(size_t)(r0 + i) * 32 + c] = acc[i];
  }
}

// Batched 32->64 GEMM (u1, u1cf, u2): relu(A @ W + b), per-slice A/W/b/C.
__global__ __launch_bounds__(256) void k_gemm_u3(
    const float* __restrict__ A0, const float* __restrict__ A1,
    const float* __restrict__ A2, const float* __restrict__ W0,
    const float* __restrict__ W1, const float* __restrict__ W2,
    const float* __restrict__ b0, const float* __restrict__ b1,
    const float* __restrict__ b2, float* __restrict__ C0,
    float* __restrict__ C1, float* __restrict__ C2) {
  __shared__ float Ws[32 * 64];
  const int slice = blockIdx.y;
  const float* __restrict__ A = slice == 0 ? A0 : (slice == 1 ? A1 : A2);
  const float* __restrict__ W = slice == 0 ? W0 : (slice == 1 ? W1 : W2);
  const float* __restrict__ bias = slice == 0 ? b0 : (slice == 1 ? b1 : b2);
  float* __restrict__ C = slice == 0 ? C0 : (slice == 1 ? C1 : C2);
  for (int i = threadIdx.x; i < 32 * 64; i += 256) Ws[i] = W[i];
  __syncthreads();
  const int c = threadIdx.x & 63;
  const int rg = threadIdx.x >> 6;
  const int r0 = blockIdx.x * 32 + rg * 8;
  float acc[8];
#pragma unroll
  for (int i = 0; i < 8; i++) acc[i] = 0.0f;
#pragma unroll 4
  for (int k = 0; k < 32; ++k) {
    float wv = Ws[k * 64 + c];
#pragma unroll
    for (int i = 0; i < 8; i++)
      acc[i] = fmaf(A[(size_t)(r0 + i) * 32 + k], wv, acc[i]);
  }
  float b = bias[c];
#pragma unroll
  for (int i = 0; i < 8; i++) {
    float v = acc[i] + b;
    C[(size_t)(r0 + i) * 64 + c] = fmaxf(v, 0.0f);
  }
}

// Batched 64->256 output GEMM (x_s_hat, x_s_cf_hat, x_ns_hat): A @ W + b.
__global__ __launch_bounds__(256) void k_gemm_o3(
    const float* __restrict__ A0, const float* __restrict__ A1,
    const float* __restrict__ A2, const float* __restrict__ W0,
    const float* __restrict__ W1, const float* __restrict__ W2,
    const float* __restrict__ b0, const float* __restrict__ b1,
    const float* __restrict__ b2, float* __restrict__ C0,
    float* __restrict__ C1, float* __restrict__ C2) {
  __shared__ float Ws[64 * 256];
  const int slice = blockIdx.y;
  const float* __restrict__ A = slice == 0 ? A0 : (slice == 1 ? A1 : A2);
  const float* __restrict__ W = slice == 0 ? W0 : (slice == 1 ? W1 : W2);
  const float* __restrict__ bias = slice == 0 ? b0 : (slice == 1 ? b1 : b2);
  float* __restrict__ C = slice == 0 ? C0 : (slice == 1 ? C1 : C2);
  for (int i = threadIdx.x; i < 64 * 256; i += 256) Ws[i] = W[i];
  __syncthreads();
  const int c = threadIdx.x;
  const int r0 = blockIdx.x * 8;
  float acc[8];
#pragma unroll
  for (int i = 0; i < 8; i++) acc[i] = 0.0f;
#pragma unroll 4
  for (int k = 0; k < 64; ++k) {
    float wv = Ws[k * 256 + c];
#pragma unroll
    for (int i = 0; i < 8; i++)
      acc[i] = fmaf(A[(size_t)(r0 + i) * 64 + k], wv, acc[i]);
  }
  float b = bias[c];
#pragma unroll
  for (int i = 0; i < 8; i++) C[(size_t)(r0 + i) * 256 + c] = acc[i] + b;
}

// hs = gns @ s_W + s_b, written directly as bf16 hi/lo split (for MFMA syrk)
__global__ __launch_bounds__(256) void k_gemm_hs(const float* __restrict__ A,
                                                 const float* __restrict__ W,
                                                 const float* __restrict__ bias,
                                                 unsigned short* __restrict__ hi,
                                                 unsigned short* __restrict__ lo) {
  __shared__ float Ws[32 * 64];
  for (int i = threadIdx.x; i < 32 * 64; i += 256) {
    int k = i / 64, c2 = i % 64;
    Ws[i] = W[k * 64 + c2];
  }
  __syncthreads();
  const int c = threadIdx.x % 64;
  const int rg = threadIdx.x / 64;
  const int r0 = blockIdx.x * 32 + rg * 8;
  float acc[8];
#pragma unroll
  for (int i = 0; i < 8; i++) acc[i] = 0.0f;
#pragma unroll 4
  for (int k = 0; k < 32; ++k) {
    float wv = Ws[k * 64 + c];
#pragma unroll
    for (int i = 0; i < 8; i++)
      acc[i] = fmaf(A[(size_t)(r0 + i) * 32 + k], wv, acc[i]);
  }
  float b = bias[c];
#pragma unroll
  for (int i = 0; i < 8; i++) {
    float v = acc[i] + b;
    unsigned short h = f2bf_rne(v);
    float l = v - bf2f(h);
    hi[(size_t)(r0 + i) * 64 + c] = h;
    lo[(size_t)(r0 + i) * 64 + c] = f2bf_rne(l);
  }
}

// ---------------------------------------------------------------- s_ = hs@hs^T
// bf16 MFMA (32x32x16), hi/lo split: hi*hi + hi*lo + lo*hi ~ fp32 accuracy.

__global__ __launch_bounds__(256) void k_syrk_mfma(
    const unsigned short* __restrict__ hhi, const unsigned short* __restrict__ hlo,
    float* __restrict__ out) {
  const int tid = threadIdx.x;
  const int lane = tid & 63;
  const int wave = tid >> 6;
  const int wy = wave >> 1, wx = wave & 1;
  const int m = lane & 31;
  const int koff = (lane >> 5) * 8;
  const size_t rb = (size_t)blockIdx.y * 128 + wy * 64;
  const size_t cb = (size_t)blockIdx.x * 128 + wx * 64;
  f32x16 acc[2][2];
#pragma unroll
  for (int i = 0; i < 2; i++)
#pragma unroll
    for (int j = 0; j < 2; j++) acc[i][j] = (f32x16)(0.0f);
#pragma unroll
  for (int k0 = 0; k0 < 64; k0 += 16) {
    bf16x8 ah[2], al[2], bh[2], bl[2];
#pragma unroll
    for (int t = 0; t < 2; t++) {
      size_t ra = (rb + t * 32 + m) * 64 + k0 + koff;
      ah[t] = *(const bf16x8*)(hhi + ra);
      al[t] = *(const bf16x8*)(hlo + ra);
      size_t rc = (cb + t * 32 + m) * 64 + k0 + koff;
      bh[t] = *(const bf16x8*)(hhi + rc);
      bl[t] = *(const bf16x8*)(hlo + rc);
    }
#pragma unroll
    for (int i = 0; i < 2; i++)
#pragma unroll
      for (int j = 0; j < 2; j++) {
        acc[i][j] = __builtin_amdgcn_mfma_f32_32x32x16_bf16(ah[i], bh[j], acc[i][j], 0, 0, 0);
        acc[i][j] = __builtin_amdgcn_mfma_f32_32x32x16_bf16(ah[i], bl[j], acc[i][j], 0, 0, 0);
        acc[i][j] = __builtin_amdgcn_mfma_f32_32x32x16_bf16(al[i], bh[j], acc[i][j], 0, 0, 0);
      }
  }
  // C/D layout (32x32): col = lane&31, row = (r&3) + 8*(r>>2) + 4*(lane>>5)
  const int rowoff = 4 * (lane >> 5);
  const int colc = lane & 31;
#pragma unroll
  for (int i = 0; i < 2; i++)
#pragma unroll
    for (int j = 0; j < 2; j++)
#pragma unroll
      for (int r = 0; r < 16; r++) {
        size_t row = rb + i * 32 + (r & 3) + 8 * (r >> 2) + rowoff;
        out[row * 12288 + cb + j * 32 + colc] = acc[i][j][r];
      }
}

// ---------------------------------------------------------------- launch

extern "C" void kernel_launch(void* const* d_in, const int* in_sizes, int n_in,
                              void* d_out, int out_size, void* d_ws,
                              size_t ws_size, hipStream_t stream) {
  (void)in_sizes; (void)n_in; (void)out_size; (void)ws_size;
  const float* x = (const float*)d_in[0];
  const int* ei = (const int*)d_in[1];
  const int* src = ei;
  const int* dst = ei + E_EDGES;
  const float* eW1 = (const float*)d_in[2];
  const float* eb1 = (const float*)d_in[3];
  const float* eW2 = (const float*)d_in[4];
  const float* eb2 = (const float*)d_in[5];
  const float* d1W1 = (const float*)d_in[6];
  const float* d1b1 = (const float*)d_in[7];
  const float* d1W2 = (const float*)d_in[8];
  const float* d1b2 = (const float*)d_in[9];
  const float* d2W1 = (const float*)d_in[10];
  const float* d2b1 = (const float*)d_in[11];
  const float* d2W2 = (const float*)d_in[12];
  const float* d2b2 = (const float*)d_in[13];
  const float* sW = (const float*)d_in[14];
  const float* sb = (const float*)d_in[15];

  float* out = (float*)d_out;
  float* out_zs = out;                  // 12288 x 32
  float* out_zns = out + 393216;        // 12288 x 32
  float* out_xs = out + 786432;         // 12288 x 256
  float* out_xns = out + 3932160;       // 12288 x 256
  float* out_xscf = out + 7077888;      // 12288 x 256
  float* out_s = out + 10223616;        // 12288 x 12288

  char* w = (char*)d_ws;
  size_t o = 0;
  auto alloc = [&](size_t bytes) -> void* {
    void* p = (void*)(w + o);
    o += (bytes + 255) & ~(size_t)255;
    return p;
  };
  int* deg = (int*)alloc(N_NODES * 4);
  int* rowptr = (int*)alloc((N_NODES + 1) * 4);
  int* cursor = (int*)alloc(N_NODES * 4);
  int* col = (int*)alloc(TOT_EDGES * 4);
  float* wgt = (float*)alloc(TOT_EDGES * 4);
  float* dinv = (float*)alloc(N_NODES * 4);
  float* coef = (float*)alloc(N_NODES * 4);
  const size_t B64 = (size_t)N_NODES * 64 * 4;
  const size_t B32 = (size_t)N_NODES * 32 * 4;
  float* slotA = (float*)alloc(B64);  // HWe1 -> HWe2 -> g1
  float* slotB = (float*)alloc(B64);  // h1 -> u1
  float* slotC = (float*)alloc(B64);  // h1cf -> u1cf
  float* slotU3 = (float*)alloc(B64); // u2
  float* slotG2 = (float*)alloc(B64); // g1cf
  float* slotG3 = (float*)alloc(B64); // g2
  float* t32 = (float*)alloc(B32);
  float* zscf = (float*)alloc(B32);
  float* gs = (float*)alloc(B32);
  float* gscf = (float*)alloc(B32);
  float* gns = (float*)alloc(B32);
  unsigned short* hhi = (unsigned short*)alloc((size_t)N_NODES * 64 * 2);
  unsigned short* hlo = (unsigned short*)alloc((size_t)N_NODES * 64 * 2);

  // ---- graph build (4)
  k_init<<<48, 256, 0, stream>>>(x, deg, coef);
  k_count<<<1536, 256, 0, stream>>>(dst, deg);
  k_scan<<<1, 1024, 0, stream>>>(deg, rowptr, cursor, dinv);
  k_fill<<<1584, 256, 0, stream>>>(src, dst, dinv, cursor, col, wgt);

  // ---- encoder (5)
  // HWe1 = x @ enc_W1
  k_gemm<256, 64, 64, 8, false, false><<<384, 256, 0, stream>>>(x, eW1, nullptr, slotA);
  // h1 = relu(A(HWe1)+b1); h1cf = relu(A(HWe1 + coef (x) W1row0)+b1) [batched]
  k_agg64_enc<<<dim3(3072, 2), 256, 0, stream>>>(slotA, rowptr, col, wgt, eb1,
                                                 coef, eW1, slotB, slotC);
  // HWe2 = h1 @ eW2 ; t32 = h1cf @ eW2[:, :32] [batched]
  k_gemm_enc2<<<dim3(384, 2), 256, 0, stream>>>(slotB, slotC, eW2, slotA, t32);
  // z = A(HWe2)+b2, split-written into out_zs / out_zns
  k_agg64<true, false, true><<<3072, 256, 0, stream>>>(slotA, rowptr, col, wgt,
                                                       eb2, out_zs, out_zns);
  // zscf = A(t32) + b2[:32]
  k_agg32<true><<<1536, 256, 0, stream>>>(t32, rowptr, col, wgt, eb2, zscf);

  // ---- decoder stage batched across the 3 independent chains (4)
  // gs = A(z_s); gscf = A(zscf); gns = A(z_ns)
  k_agg32_b3<<<dim3(1536, 3), 256, 0, stream>>>(out_zs, zscf, out_zns, rowptr,
                                                col, wgt, gs, gscf, gns);
  // hs = gns @ s_W + s_b, bf16 hi/lo (feeds the syrk long pole)
  k_gemm_hs<<<384, 256, 0, stream>>>(gns, sW, sb, hhi, hlo);
  // u1 = relu(gs@d1W1+b); u1cf = relu(gscf@d1W1+b); u2 = relu(gns@d2W1+b)
  k_gemm_u3<<<dim3(384, 3), 256, 0, stream>>>(gs, gscf, gns, d1W1, d1W1, d2W1,
                                              d1b1, d1b1, d2b1, slotB, slotC,
                                              slotU3);
  // g1 = A(u1); g1cf = A(u1cf); g2 = A(u2)
  k_agg64_dec3<<<dim3(3072, 3), 256, 0, stream>>>(slotB, slotC, slotU3, rowptr,
                                                  col, wgt, slotA, slotG2,
                                                  slotG3);
  // x_s_hat = g1@d1W2+b ; x_s_cf_hat = g1cf@d1W2+b ; x_ns_hat = g2@d2W2+b
  k_gemm_o3<<<dim3(1536, 3), 256, 0, stream>>>(slotA, slotG2, slotG3, d1W2,
                                               d1W2, d2W2, d1b2, d1b2, d2b2,
                                               out_xs, out_xscf, out_xns);

  // ---- s_ = hs @ hs^T  (bf16 MFMA, hi/lo corrected) (1)
  k_syrk_mfma<<<dim3(96, 96), 256, 0, stream>>>(hhi, hlo, out_s);
}

// Round 6
// 987.979 us; speedup vs baseline: 1.0887x; 1.0112x over previous
//
#include <hip/hip_runtime.h>

#define N_NODES 12288
#define IN_DIM_ 256
#define HID_ 64
#define E_EDGES 393216
#define TOT_EDGES (E_EDGES + N_NODES)  // 405504

typedef __attribute__((ext_vector_type(8))) short bf16x8;
typedef __attribute__((ext_vector_type(16))) float f32x16;

__device__ inline unsigned short f2bf_rne(float f) {
  unsigned int u = __float_as_uint(f);
  unsigned int r = u + 0x7fffu + ((u >> 16) & 1u);
  return (unsigned short)(r >> 16);
}
__device__ inline float bf2f(unsigned short h) {
  return __uint_as_float(((unsigned int)h) << 16);
}

// ---------------------------------------------------------------- graph build

__global__ __launch_bounds__(256) void k_init(const float* __restrict__ x,
                                              int* __restrict__ deg,
                                              float* __restrict__ coef) {
  int i = blockIdx.x * 256 + threadIdx.x;
  if (i < N_NODES) {
    deg[i] = 1;  // self loop
    coef[i] = 1.0f - 2.0f * x[(size_t)i * IN_DIM_];
  }
}

__global__ __launch_bounds__(256) void k_count(const int* __restrict__ dst,
                                               int* __restrict__ deg) {
  int e = blockIdx.x * 256 + threadIdx.x;
  if (e < E_EDGES) atomicAdd(&deg[dst[e]], 1);
}

__global__ __launch_bounds__(1024) void k_scan(const int* __restrict__ deg,
                                               int* __restrict__ rowptr,
                                               int* __restrict__ cursor,
                                               float* __restrict__ dinv) {
  __shared__ int sh[1024];
  const int t = threadIdx.x;
  int loc[12];
  int s = 0;
#pragma unroll
  for (int i = 0; i < 12; i++) {
    int d = deg[t * 12 + i];
    dinv[t * 12 + i] = 1.0f / sqrtf((float)d);
    loc[i] = s;
    s += d;
  }
  sh[t] = s;
  __syncthreads();
  for (int off = 1; off < 1024; off <<= 1) {
    int v = (t >= off) ? sh[t - off] : 0;
    __syncthreads();
    sh[t] += v;
    __syncthreads();
  }
  int base = sh[t] - s;  // exclusive
#pragma unroll
  for (int i = 0; i < 12; i++) {
    int v = base + loc[i];
    rowptr[t * 12 + i] = v;
    cursor[t * 12 + i] = v;
  }
  if (t == 1023) rowptr[N_NODES] = sh[1023];
}

__global__ __launch_bounds__(256) void k_fill(const int* __restrict__ src,
                                              const int* __restrict__ dst,
                                              const float* __restrict__ dinv,
                                              int* __restrict__ cursor,
                                              int* __restrict__ col,
                                              float* __restrict__ wgt) {
  int e = blockIdx.x * 256 + threadIdx.x;
  if (e < E_EDGES) {
    int s = src[e], d = dst[e];
    int pos = atomicAdd(&cursor[d], 1);
    col[pos] = s;
    wgt[pos] = dinv[s] * dinv[d];
  } else if (e < TOT_EDGES) {
    int i = e - E_EDGES;
    int pos = atomicAdd(&cursor[i], 1);
    col[pos] = i;
    float di = dinv[i];
    wgt[pos] = di * di;
  }
}

// ---------------------------------------------------------------- aggregation
// One wave per node, MLP-8 (8 independent gathers in flight).

// Batched encoder agg: slice 0 = h1 (plain), slice 1 = h1cf (rank-1 fused).
__global__ __launch_bounds__(256) void k_agg64_enc(
    const float* __restrict__ in, const int* __restrict__ rowptr,
    const int* __restrict__ col, const float* __restrict__ wgt,
    const float* __restrict__ bias, const float* __restrict__ coef,
    const float* __restrict__ wrow, float* __restrict__ out0,
    float* __restrict__ out1) {
  const int lane = threadIdx.x & 63;
  int node = blockIdx.x * 4 + (threadIdx.x >> 6);
  node = __builtin_amdgcn_readfirstlane(node);
  const int slice = blockIdx.y;
  const float wr = slice ? wrow[lane] : 0.0f;
  const int start = rowptr[node];
  const int end = rowptr[node + 1];
  float a0 = 0.0f, a1 = 0.0f, a2 = 0.0f, a3 = 0.0f;
  int e = start;
  for (; e + 8 <= end; e += 8) {
    int c0 = col[e + 0], c1 = col[e + 1], c2 = col[e + 2], c3 = col[e + 3];
    int c4 = col[e + 4], c5 = col[e + 5], c6 = col[e + 6], c7 = col[e + 7];
    float w0 = wgt[e + 0], w1 = wgt[e + 1], w2 = wgt[e + 2], w3 = wgt[e + 3];
    float w4 = wgt[e + 4], w5 = wgt[e + 5], w6 = wgt[e + 6], w7 = wgt[e + 7];
    float v0 = in[(size_t)c0 * 64 + lane];
    float v1 = in[(size_t)c1 * 64 + lane];
    float v2 = in[(size_t)c2 * 64 + lane];
    float v3 = in[(size_t)c3 * 64 + lane];
    float v4 = in[(size_t)c4 * 64 + lane];
    float v5 = in[(size_t)c5 * 64 + lane];
    float v6 = in[(size_t)c6 * 64 + lane];
    float v7 = in[(size_t)c7 * 64 + lane];
    v0 = fmaf(coef[c0], wr, v0);
    v1 = fmaf(coef[c1], wr, v1);
    v2 = fmaf(coef[c2], wr, v2);
    v3 = fmaf(coef[c3], wr, v3);
    v4 = fmaf(coef[c4], wr, v4);
    v5 = fmaf(coef[c5], wr, v5);
    v6 = fmaf(coef[c6], wr, v6);
    v7 = fmaf(coef[c7], wr, v7);
    a0 = fmaf(w0, v0, a0);
    a1 = fmaf(w1, v1, a1);
    a2 = fmaf(w2, v2, a2);
    a3 = fmaf(w3, v3, a3);
    a0 = fmaf(w4, v4, a0);
    a1 = fmaf(w5, v5, a1);
    a2 = fmaf(w6, v6, a2);
    a3 = fmaf(w7, v7, a3);
  }
  for (; e < end; ++e) {
    int c = col[e];
    float v = in[(size_t)c * 64 + lane];
    v = fmaf(coef[c], wr, v);
    a0 = fmaf(wgt[e], v, a0);
  }
  float acc = (a0 + a1) + (a2 + a3) + bias[lane];
  acc = fmaxf(acc, 0.0f);
  (slice ? out1 : out0)[(size_t)node * 64 + lane] = acc;
}

// Merged z-stage: y==0 (3072 blocks): z = A(HWe2)+b2 split into zs/zns;
// y==1 (first 1536 blocks): zscf = A(t32) + b2[:32].
__global__ __launch_bounds__(256) void k_agg_z(
    const float* __restrict__ in64, const float* __restrict__ in32,
    const int* __restrict__ rowptr, const int* __restrict__ col,
    const float* __restrict__ wgt, const float* __restrict__ bias,
    float* __restrict__ out_zs, float* __restrict__ out_zns,
    float* __restrict__ out_zscf) {
  if (blockIdx.y == 0) {
    const int lane = threadIdx.x & 63;
    int node = blockIdx.x * 4 + (threadIdx.x >> 6);
    node = __builtin_amdgcn_readfirstlane(node);
    const int start = rowptr[node];
    const int end = rowptr[node + 1];
    float a0 = 0.0f, a1 = 0.0f, a2 = 0.0f, a3 = 0.0f;
    int e = start;
    for (; e + 8 <= end; e += 8) {
      int c0 = col[e + 0], c1 = col[e + 1], c2 = col[e + 2], c3 = col[e + 3];
      int c4 = col[e + 4], c5 = col[e + 5], c6 = col[e + 6], c7 = col[e + 7];
      float w0 = wgt[e + 0], w1 = wgt[e + 1], w2 = wgt[e + 2], w3 = wgt[e + 3];
      float w4 = wgt[e + 4], w5 = wgt[e + 5], w6 = wgt[e + 6], w7 = wgt[e + 7];
      float v0 = in64[(size_t)c0 * 64 + lane];
      float v1 = in64[(size_t)c1 * 64 + lane];
      float v2 = in64[(size_t)c2 * 64 + lane];
      float v3 = in64[(size_t)c3 * 64 + lane];
      float v4 = in64[(size_t)c4 * 64 + lane];
      float v5 = in64[(size_t)c5 * 64 + lane];
      float v6 = in64[(size_t)c6 * 64 + lane];
      float v7 = in64[(size_t)c7 * 64 + lane];
      a0 = fmaf(w0, v0, a0);
      a1 = fmaf(w1, v1, a1);
      a2 = fmaf(w2, v2, a2);
      a3 = fmaf(w3, v3, a3);
      a0 = fmaf(w4, v4, a0);
      a1 = fmaf(w5, v5, a1);
      a2 = fmaf(w6, v6, a2);
      a3 = fmaf(w7, v7, a3);
    }
    for (; e < end; ++e) {
      int c = col[e];
      a0 = fmaf(wgt[e], in64[(size_t)c * 64 + lane], a0);
    }
    float acc = (a0 + a1) + (a2 + a3) + bias[lane];
    if (lane < 32)
      out_zs[(size_t)node * 32 + lane] = acc;
    else
      out_zns[(size_t)node * 32 + (lane - 32)] = acc;
  } else {
    if (blockIdx.x >= 1536) return;
    const int lane = threadIdx.x & 31;
    const int node = blockIdx.x * 8 + (threadIdx.x >> 5);
    const int start = rowptr[node];
    const int end = rowptr[node + 1];
    float a0 = 0.0f, a1 = 0.0f, a2 = 0.0f, a3 = 0.0f;
    int e = start;
    for (; e + 8 <= end; e += 8) {
      int c0 = col[e + 0], c1 = col[e + 1], c2 = col[e + 2], c3 = col[e + 3];
      int c4 = col[e + 4], c5 = col[e + 5], c6 = col[e + 6], c7 = col[e + 7];
      float w0 = wgt[e + 0], w1 = wgt[e + 1], w2 = wgt[e + 2], w3 = wgt[e + 3];
      float w4 = wgt[e + 4], w5 = wgt[e + 5], w6 = wgt[e + 6], w7 = wgt[e + 7];
      a0 = fmaf(w0, in32[(size_t)c0 * 32 + lane], a0);
      a1 = fmaf(w1, in32[(size_t)c1 * 32 + lane], a1);
      a2 = fmaf(w2, in32[(size_t)c2 * 32 + lane], a2);
      a3 = fmaf(w3, in32[(size_t)c3 * 32 + lane], a3);
      a0 = fmaf(w4, in32[(size_t)c4 * 32 + lane], a0);
      a1 = fmaf(w5, in32[(size_t)c5 * 32 + lane], a1);
      a2 = fmaf(w6, in32[(size_t)c6 * 32 + lane], a2);
      a3 = fmaf(w7, in32[(size_t)c7 * 32 + lane], a3);
    }
    for (; e < end; ++e)
      a0 = fmaf(wgt[e], in32[(size_t)col[e] * 32 + lane], a0);
    out_zscf[(size_t)node * 32 + lane] = (a0 + a1) + (a2 + a3) + bias[lane];
  }
}

// Batched plain agg64 over three independent decoder chains (blockIdx.y).
__global__ __launch_bounds__(256) void k_agg64_dec3(
    const float* __restrict__ in0, const float* __restrict__ in1,
    const float* __restrict__ in2, const int* __restrict__ rowptr,
    const int* __restrict__ col, const float* __restrict__ wgt,
    float* __restrict__ out0, float* __restrict__ out1,
    float* __restrict__ out2) {
  const int lane = threadIdx.x & 63;
  int node = blockIdx.x * 4 + (threadIdx.x >> 6);
  node = __builtin_amdgcn_readfirstlane(node);
  const int slice = blockIdx.y;
  const float* __restrict__ in = slice == 0 ? in0 : (slice == 1 ? in1 : in2);
  float* __restrict__ out = slice == 0 ? out0 : (slice == 1 ? out1 : out2);
  const int start = rowptr[node];
  const int end = rowptr[node + 1];
  float a0 = 0.0f, a1 = 0.0f, a2 = 0.0f, a3 = 0.0f;
  int e = start;
  for (; e + 8 <= end; e += 8) {
    int c0 = col[e + 0], c1 = col[e + 1], c2 = col[e + 2], c3 = col[e + 3];
    int c4 = col[e + 4], c5 = col[e + 5], c6 = col[e + 6], c7 = col[e + 7];
    float w0 = wgt[e + 0], w1 = wgt[e + 1], w2 = wgt[e + 2], w3 = wgt[e + 3];
    float w4 = wgt[e + 4], w5 = wgt[e + 5], w6 = wgt[e + 6], w7 = wgt[e + 7];
    float v0 = in[(size_t)c0 * 64 + lane];
    float v1 = in[(size_t)c1 * 64 + lane];
    float v2 = in[(size_t)c2 * 64 + lane];
    float v3 = in[(size_t)c3 * 64 + lane];
    float v4 = in[(size_t)c4 * 64 + lane];
    float v5 = in[(size_t)c5 * 64 + lane];
    float v6 = in[(size_t)c6 * 64 + lane];
    float v7 = in[(size_t)c7 * 64 + lane];
    a0 = fmaf(w0, v0, a0);
    a1 = fmaf(w1, v1, a1);
    a2 = fmaf(w2, v2, a2);
    a3 = fmaf(w3, v3, a3);
    a0 = fmaf(w4, v4, a0);
    a1 = fmaf(w5, v5, a1);
    a2 = fmaf(w6, v6, a2);
    a3 = fmaf(w7, v7, a3);
  }
  for (; e < end; ++e) {
    int c = col[e];
    a0 = fmaf(wgt[e], in[(size_t)c * 64 + lane], a0);
  }
  float acc = (a0 + a1) + (a2 + a3);
  out[(size_t)node * 64 + lane] = acc;
}

// Batched agg32 for gs / gscf / gns (all bias-free).
__global__ __launch_bounds__(256) void k_agg32_b3(
    const float* __restrict__ in0, const float* __restrict__ in1,
    const float* __restrict__ in2, const int* __restrict__ rowptr,
    const int* __restrict__ col, const float* __restrict__ wgt,
    float* __restrict__ out0, float* __restrict__ out1,
    float* __restrict__ out2) {
  const int lane = threadIdx.x & 31;
  const int node = blockIdx.x * 8 + (threadIdx.x >> 5);
  const int slice = blockIdx.y;
  const float* __restrict__ in = slice == 0 ? in0 : (slice == 1 ? in1 : in2);
  float* __restrict__ out = slice == 0 ? out0 : (slice == 1 ? out1 : out2);
  const int start = rowptr[node];
  const int end = rowptr[node + 1];
  float a0 = 0.0f, a1 = 0.0f, a2 = 0.0f, a3 = 0.0f;
  int e = start;
  for (; e + 8 <= end; e += 8) {
    int c0 = col[e + 0], c1 = col[e + 1], c2 = col[e + 2], c3 = col[e + 3];
    int c4 = col[e + 4], c5 = col[e + 5], c6 = col[e + 6], c7 = col[e + 7];
    float w0 = wgt[e + 0], w1 = wgt[e + 1], w2 = wgt[e + 2], w3 = wgt[e + 3];
    float w4 = wgt[e + 4], w5 = wgt[e + 5], w6 = wgt[e + 6], w7 = wgt[e + 7];
    a0 = fmaf(w0, in[(size_t)c0 * 32 + lane], a0);
    a1 = fmaf(w1, in[(size_t)c1 * 32 + lane], a1);
    a2 = fmaf(w2, in[(size_t)c2 * 32 + lane], a2);
    a3 = fmaf(w3, in[(size_t)c3 * 32 + lane], a3);
    a0 = fmaf(w4, in[(size_t)c4 * 32 + lane], a0);
    a1 = fmaf(w5, in[(size_t)c5 * 32 + lane], a1);
    a2 = fmaf(w6, in[(size_t)c6 * 32 + lane], a2);
    a3 = fmaf(w7, in[(size_t)c7 * 32 + lane], a3);
  }
  for (; e < end; ++e) a0 = fmaf(wgt[e], in[(size_t)col[e] * 32 + lane], a0);
  out[(size_t)node * 32 + lane] = (a0 + a1) + (a2 + a3);
}

// ---------------------------------------------------------------- small GEMM
// v4: float4 A-loads (4x fewer VMEM instrs), K-chunked 16KB LDS staging,
// RPT=4 with doubled grids for 2x wave count.

template <int K, int KC, int NF, int LDW, int RPT, bool BIAS, bool RELU>
__global__ __launch_bounds__(256) void k_gemm_v4(const float* __restrict__ A,
                                                 const float* __restrict__ W,
                                                 const float* __restrict__ bias,
                                                 float* __restrict__ C) {
  __shared__ float Ws[KC * NF];
  constexpr int G = 256 / NF;
  const int c = threadIdx.x % NF;
  const int rg = threadIdx.x / NF;
  const int r0 = blockIdx.x * (G * RPT) + rg * RPT;
  float acc[RPT];
#pragma unroll
  for (int i = 0; i < RPT; i++) acc[i] = 0.0f;
  for (int k0 = 0; k0 < K; k0 += KC) {
    for (int t = threadIdx.x; t < KC * NF; t += 256)
      Ws[t] = W[(k0 + t / NF) * LDW + (t % NF)];
    __syncthreads();
#pragma unroll 2
    for (int k = 0; k < KC; k += 4) {
      float4 a[RPT];
#pragma unroll
      for (int i = 0; i < RPT; i++)
        a[i] = *(const float4*)&A[(size_t)(r0 + i) * K + k0 + k];
      float w0 = Ws[(k + 0) * NF + c];
      float w1 = Ws[(k + 1) * NF + c];
      float w2 = Ws[(k + 2) * NF + c];
      float w3 = Ws[(k + 3) * NF + c];
#pragma unroll
      for (int i = 0; i < RPT; i++) {
        acc[i] = fmaf(a[i].x, w0, acc[i]);
        acc[i] = fmaf(a[i].y, w1, acc[i]);
        acc[i] = fmaf(a[i].z, w2, acc[i]);
        acc[i] = fmaf(a[i].w, w3, acc[i]);
      }
    }
    __syncthreads();
  }
  float b = BIAS ? bias[c] : 0.0f;
#pragma unroll
  for (int i = 0; i < RPT; i++) {
    float v = acc[i] + b;
    if (RELU) v = fmaxf(v, 0.0f);
    C[(size_t)(r0 + i) * NF + c] = v;
  }
}

// Batched encoder stage-2 (K=64, NF=64): slice 0: HWe2 = h1 @ eW2 (full);
// slice 1: t32 = h1cf @ eW2[:, :32] (writes only c<32, stride 32).
__global__ __launch_bounds__(256) void k_gemm_enc2(
    const float* __restrict__ A0, const float* __restrict__ A1,
    const float* __restrict__ W, float* __restrict__ C0,
    float* __restrict__ C1) {
  __shared__ float Ws[64 * 64];
  const int slice = blockIdx.y;
  const float* __restrict__ A = slice ? A1 : A0;
  for (int i = threadIdx.x; i < 64 * 64; i += 256) Ws[i] = W[i];
  __syncthreads();
  const int c = threadIdx.x & 63;
  const int rg = threadIdx.x >> 6;
  const int r0 = blockIdx.x * 16 + rg * 4;
  float acc[4];
#pragma unroll
  for (int i = 0; i < 4; i++) acc[i] = 0.0f;
#pragma unroll 2
  for (int k = 0; k < 64; k += 4) {
    float4 a[4];
#pragma unroll
    for (int i = 0; i < 4; i++)
      a[i] = *(const float4*)&A[(size_t)(r0 + i) * 64 + k];
    float w0 = Ws[(k + 0) * 64 + c];
    float w1 = Ws[(k + 1) * 64 + c];
    float w2 = Ws[(k + 2) * 64 + c];
    float w3 = Ws[(k + 3) * 64 + c];
#pragma unroll
    for (int i = 0; i < 4; i++) {
      acc[i] = fmaf(a[i].x, w0, acc[i]);
      acc[i] = fmaf(a[i].y, w1, acc[i]);
      acc[i] = fmaf(a[i].z, w2, acc[i]);
      acc[i] = fmaf(a[i].w, w3, acc[i]);
    }
  }
  if (slice == 0) {
#pragma unroll
    for (int i = 0; i < 4; i++) C0[(size_t)(r0 + i) * 64 + c] = acc[i];
  } else if (c < 32) {
#pragma unroll
    for (int i = 0; i < 4; i++) C1[(size_t)(r0 + i) * 32 + c] = acc[i];
  }
}

// Batched 32->64 GEMM, 4 slices: 0..2 = relu(g@W+b) (u1,u1cf,u2);
// slice 3 = hs = gns@s_W+s_b written as bf16 hi/lo (feeds syrk).
__global__ __launch_bounds__(256) void k_gemm_u4(
    const float* __restrict__ A0, const float* __restrict__ A1,
    const float* __restrict__ A2, const float* __restrict__ W0,
    const float* __restrict__ W1, const float* __restrict__ W2,
    const float* __restrict__ W3, const float* __restrict__ b0,
    const float* __restrict__ b1, const float* __restrict__ b2,
    const float* __restrict__ b3, float* __restrict__ C0,
    float* __restrict__ C1, float* __restrict__ C2,
    unsigned short* __restrict__ hi, unsigned short* __restrict__ lo) {
  __shared__ float Ws[32 * 64];
  const int slice = blockIdx.y;
  const float* __restrict__ A =
      slice == 0 ? A0 : (slice == 1 ? A1 : A2);  // slice 3 uses A2 (gns)
  const float* __restrict__ W =
      slice == 0 ? W0 : (slice == 1 ? W1 : (slice == 2 ? W2 : W3));
  const float* __restrict__ bias =
      slice == 0 ? b0 : (slice == 1 ? b1 : (slice == 2 ? b2 : b3));
  for (int i = threadIdx.x; i < 32 * 64; i += 256) Ws[i] = W[i];
  __syncthreads();
  const int c = threadIdx.x & 63;
  const int rg = threadIdx.x >> 6;
  const int r0 = blockIdx.x * 16 + rg * 4;
  float acc[4];
#pragma unroll
  for (int i = 0; i < 4; i++) acc[i] = 0.0f;
#pragma unroll 2
  for (int k = 0; k < 32; k += 4) {
    float4 a[4];
#pragma unroll
    for (int i = 0; i < 4; i++)
      a[i] = *(const float4*)&A[(size_t)(r0 + i) * 32 + k];
    float w0 = Ws[(k + 0) * 64 + c];
    float w1 = Ws[(k + 1) * 64 + c];
    float w2 = Ws[(k + 2) * 64 + c];
    float w3 = Ws[(k + 3) * 64 + c];
#pragma unroll
    for (int i = 0; i < 4; i++) {
      acc[i] = fmaf(a[i].x, w0, acc[i]);
      acc[i] = fmaf(a[i].y, w1, acc[i]);
      acc[i] = fmaf(a[i].z, w2, acc[i]);
      acc[i] = fmaf(a[i].w, w3, acc[i]);
    }
  }
  float b = bias[c];
  if (slice < 3) {
    float* __restrict__ C = slice == 0 ? C0 : (slice == 1 ? C1 : C2);
#pragma unroll
    for (int i = 0; i < 4; i++)
      C[(size_t)(r0 + i) * 64 + c] = fmaxf(acc[i] + b, 0.0f);
  } else {
#pragma unroll
    for (int i = 0; i < 4; i++) {
      float v = acc[i] + b;
      unsigned short h = f2bf_rne(v);
      float l = v - bf2f(h);
      hi[(size_t)(r0 + i) * 64 + c] = h;
      lo[(size_t)(r0 + i) * 64 + c] = f2bf_rne(l);
    }
  }
}

// Batched 64->256 output GEMM, column-blocked: thread computes 4 rows x 4 cols
// (cols c, c+64, c+128, c+192). K-chunked 16KB LDS staging.
__global__ __launch_bounds__(256) void k_gemm_o3(
    const float* __restrict__ A0, const float* __restrict__ A1,
    const float* __restrict__ A2, const float* __restrict__ W0,
    const float* __restrict__ W1, const float* __restrict__ W2,
    const float* __restrict__ b0, const float* __restrict__ b1,
    const float* __restrict__ b2, float* __restrict__ C0,
    float* __restrict__ C1, float* __restrict__ C2) {
  __shared__ float Ws[16 * 256];
  const int slice = blockIdx.y;
  const float* __restrict__ A = slice == 0 ? A0 : (slice == 1 ? A1 : A2);
  const float* __restrict__ W = slice == 0 ? W0 : (slice == 1 ? W1 : W2);
  const float* __restrict__ bias = slice == 0 ? b0 : (slice == 1 ? b1 : b2);
  float* __restrict__ C = slice == 0 ? C0 : (slice == 1 ? C1 : C2);
  const int c = threadIdx.x & 63;
  const int rg = threadIdx.x >> 6;
  const int r0 = blockIdx.x * 16 + rg * 4;
  float acc[4][4];
#pragma unroll
  for (int i = 0; i < 4; i++)
#pragma unroll
    for (int j = 0; j < 4; j++) acc[i][j] = 0.0f;
  for (int k0 = 0; k0 < 64; k0 += 16) {
    for (int t = threadIdx.x; t < 16 * 256; t += 256)
      Ws[t] = W[(k0 + (t >> 8)) * 256 + (t & 255)];
    __syncthreads();
#pragma unroll
    for (int k = 0; k < 16; k += 4) {
      float4 a[4];
#pragma unroll
      for (int i = 0; i < 4; i++)
        a[i] = *(const float4*)&A[(size_t)(r0 + i) * 64 + k0 + k];
#pragma unroll
      for (int kk = 0; kk < 4; kk++) {
        float w0 = Ws[(k + kk) * 256 + c];
        float w1 = Ws[(k + kk) * 256 + c + 64];
        float w2 = Ws[(k + kk) * 256 + c + 128];
        float w3 = Ws[(k + kk) * 256 + c + 192];
#pragma unroll
        for (int i = 0; i < 4; i++) {
          float av = kk == 0 ? a[i].x : (kk == 1 ? a[i].y : (kk == 2 ? a[i].z : a[i].w));
          acc[i][0] = fmaf(av, w0, acc[i][0]);
          acc[i][1] = fmaf(av, w1, acc[i][1]);
          acc[i][2] = fmaf(av, w2, acc[i][2]);
          acc[i][3] = fmaf(av, w3, acc[i][3]);
        }
      }
    }
    __syncthreads();
  }
  float bb0 = bias[c], bb1 = bias[c + 64], bb2 = bias[c + 128], bb3 = bias[c + 192];
#pragma unroll
  for (int i = 0; i < 4; i++) {
    size_t base = (size_t)(r0 + i) * 256;
    C[base + c] = acc[i][0] + bb0;
    C[base + c + 64] = acc[i][1] + bb1;
    C[base + c + 128] = acc[i][2] + bb2;
    C[base + c + 192] = acc[i][3] + bb3;
  }
}

// ---------------------------------------------------------------- s_ = hs@hs^T
// bf16 MFMA (32x32x16), hi/lo split: hi*hi + hi*lo + lo*hi ~ fp32 accuracy.

__global__ __launch_bounds__(256) void k_syrk_mfma(
    const unsigned short* __restrict__ hhi, const unsigned short* __restrict__ hlo,
    float* __restrict__ out) {
  const int tid = threadIdx.x;
  const int lane = tid & 63;
  const int wave = tid >> 6;
  const int wy = wave >> 1, wx = wave & 1;
  const int m = lane & 31;
  const int koff = (lane >> 5) * 8;
  const size_t rb = (size_t)blockIdx.y * 128 + wy * 64;
  const size_t cb = (size_t)blockIdx.x * 128 + wx * 64;
  f32x16 acc[2][2];
#pragma unroll
  for (int i = 0; i < 2; i++)
#pragma unroll
    for (int j = 0; j < 2; j++) acc[i][j] = (f32x16)(0.0f);
#pragma unroll
  for (int k0 = 0; k0 < 64; k0 += 16) {
    bf16x8 ah[2], al[2], bh[2], bl[2];
#pragma unroll
    for (int t = 0; t < 2; t++) {
      size_t ra = (rb + t * 32 + m) * 64 + k0 + koff;
      ah[t] = *(const bf16x8*)(hhi + ra);
      al[t] = *(const bf16x8*)(hlo + ra);
      size_t rc = (cb + t * 32 + m) * 64 + k0 + koff;
      bh[t] = *(const bf16x8*)(hhi + rc);
      bl[t] = *(const bf16x8*)(hlo + rc);
    }
#pragma unroll
    for (int i = 0; i < 2; i++)
#pragma unroll
      for (int j = 0; j < 2; j++) {
        acc[i][j] = __builtin_amdgcn_mfma_f32_32x32x16_bf16(ah[i], bh[j], acc[i][j], 0, 0, 0);
        acc[i][j] = __builtin_amdgcn_mfma_f32_32x32x16_bf16(ah[i], bl[j], acc[i][j], 0, 0, 0);
        acc[i][j] = __builtin_amdgcn_mfma_f32_32x32x16_bf16(al[i], bh[j], acc[i][j], 0, 0, 0);
      }
  }
  // C/D layout (32x32): col = lane&31, row = (r&3) + 8*(r>>2) + 4*(lane>>5)
  const int rowoff = 4 * (lane >> 5);
  const int colc = lane & 31;
#pragma unroll
  for (int i = 0; i < 2; i++)
#pragma unroll
    for (int j = 0; j < 2; j++)
#pragma unroll
      for (int r = 0; r < 16; r++) {
        size_t row = rb + i * 32 + (r & 3) + 8 * (r >> 2) + rowoff;
        out[row * 12288 + cb + j * 32 + colc] = acc[i][j][r];
      }
}

// ---------------------------------------------------------------- launch

extern "C" void kernel_launch(void* const* d_in, const int* in_sizes, int n_in,
                              void* d_out, int out_size, void* d_ws,
                              size_t ws_size, hipStream_t stream) {
  (void)in_sizes; (void)n_in; (void)out_size; (void)ws_size;
  const float* x = (const float*)d_in[0];
  const int* ei = (const int*)d_in[1];
  const int* src = ei;
  const int* dst = ei + E_EDGES;
  const float* eW1 = (const float*)d_in[2];
  const float* eb1 = (const float*)d_in[3];
  const float* eW2 = (const float*)d_in[4];
  const float* eb2 = (const float*)d_in[5];
  const float* d1W1 = (const float*)d_in[6];
  const float* d1b1 = (const float*)d_in[7];
  const float* d1W2 = (const float*)d_in[8];
  const float* d1b2 = (const float*)d_in[9];
  const float* d2W1 = (const float*)d_in[10];
  const float* d2b1 = (const float*)d_in[11];
  const float* d2W2 = (const float*)d_in[12];
  const float* d2b2 = (const float*)d_in[13];
  const float* sW = (const float*)d_in[14];
  const float* sb = (const float*)d_in[15];

  float* out = (float*)d_out;
  float* out_zs = out;                  // 12288 x 32
  float* out_zns = out + 393216;        // 12288 x 32
  float* out_xs = out + 786432;         // 12288 x 256
  float* out_xns = out + 3932160;       // 12288 x 256
  float* out_xscf = out + 7077888;      // 12288 x 256
  float* out_s = out + 10223616;        // 12288 x 12288

  char* w = (char*)d_ws;
  size_t o = 0;
  auto alloc = [&](size_t bytes) -> void* {
    void* p = (void*)(w + o);
    o += (bytes + 255) & ~(size_t)255;
    return p;
  };
  int* deg = (int*)alloc(N_NODES * 4);
  int* rowptr = (int*)alloc((N_NODES + 1) * 4);
  int* cursor = (int*)alloc(N_NODES * 4);
  int* col = (int*)alloc(TOT_EDGES * 4);
  float* wgt = (float*)alloc(TOT_EDGES * 4);
  float* dinv = (float*)alloc(N_NODES * 4);
  float* coef = (float*)alloc(N_NODES * 4);
  const size_t B64 = (size_t)N_NODES * 64 * 4;
  const size_t B32 = (size_t)N_NODES * 32 * 4;
  float* slotA = (float*)alloc(B64);  // HWe1 -> HWe2 -> g1
  float* slotB = (float*)alloc(B64);  // h1 -> u1
  float* slotC = (float*)alloc(B64);  // h1cf -> u1cf
  float* slotU3 = (float*)alloc(B64); // u2
  float* slotG2 = (float*)alloc(B64); // g1cf
  float* slotG3 = (float*)alloc(B64); // g2
  float* t32 = (float*)alloc(B32);
  float* zscf = (float*)alloc(B32);
  float* gs = (float*)alloc(B32);
  float* gscf = (float*)alloc(B32);
  float* gns = (float*)alloc(B32);
  unsigned short* hhi = (unsigned short*)alloc((size_t)N_NODES * 64 * 2);
  unsigned short* hlo = (unsigned short*)alloc((size_t)N_NODES * 64 * 2);

  // ---- graph build (4)
  k_init<<<48, 256, 0, stream>>>(x, deg, coef);
  k_count<<<1536, 256, 0, stream>>>(dst, deg);
  k_scan<<<1, 1024, 0, stream>>>(deg, rowptr, cursor, dinv);
  k_fill<<<1584, 256, 0, stream>>>(src, dst, dinv, cursor, col, wgt);

  // ---- encoder (4)
  // HWe1 = x @ enc_W1  (K=256, chunked LDS, float4 loads)
  k_gemm_v4<256, 64, 64, 64, 4, false, false><<<768, 256, 0, stream>>>(
      x, eW1, nullptr, slotA);
  // h1 = relu(A(HWe1)+b1); h1cf = relu(A(HWe1 + coef (x) W1row0)+b1) [batched]
  k_agg64_enc<<<dim3(3072, 2), 256, 0, stream>>>(slotA, rowptr, col, wgt, eb1,
                                                 coef, eW1, slotB, slotC);
  // HWe2 = h1 @ eW2 ; t32 = h1cf @ eW2[:, :32] [batched]
  k_gemm_enc2<<<dim3(768, 2), 256, 0, stream>>>(slotB, slotC, eW2, slotA, t32);
  // z = A(HWe2)+b2 split into zs/zns ; zscf = A(t32)+b2[:32] [merged]
  k_agg_z<<<dim3(3072, 2), 256, 0, stream>>>(slotA, t32, rowptr, col, wgt,
                                             eb2, out_zs, out_zns, zscf);

  // ---- decoder stage batched across the 3 independent chains (4)
  // gs = A(z_s); gscf = A(zscf); gns = A(z_ns)
  k_agg32_b3<<<dim3(1536, 3), 256, 0, stream>>>(out_zs, zscf, out_zns, rowptr,
                                                col, wgt, gs, gscf, gns);
  // u1,u1cf,u2 = relu(g@W+b); hs = gns@s_W+s_b -> bf16 hi/lo [4 slices]
  k_gemm_u4<<<dim3(768, 4), 256, 0, stream>>>(gs, gscf, gns, d1W1, d1W1, d2W1,
                                              sW, d1b1, d1b1, d2b1, sb, slotB,
                                              slotC, slotU3, hhi, hlo);
  // g1 = A(u1); g1cf = A(u1cf); g2 = A(u2)
  k_agg64_dec3<<<dim3(3072, 3), 256, 0, stream>>>(slotB, slotC, slotU3, rowptr,
                                                  col, wgt, slotA, slotG2,
                                                  slotG3);
  // x_s_hat / x_s_cf_hat / x_ns_hat  (column-blocked, chunked LDS)
  k_gemm_o3<<<dim3(768, 3), 256, 0, stream>>>(slotA, slotG2, slotG3, d1W2,
                                              d1W2, d2W2, d1b2, d1b2, d2b2,
                                              out_xs, out_xscf, out_xns);

  // ---- s_ = hs @ hs^T  (bf16 MFMA, hi/lo corrected) (1)
  k_syrk_mfma<<<dim3(96, 96), 256, 0, stream>>>(hhi, hlo, out_s);
}

// Round 7
// 965.914 us; speedup vs baseline: 1.1136x; 1.0228x over previous
//
#include <hip/hip_runtime.h>

#define N_NODES 12288
#define IN_DIM_ 256
#define HID_ 64
#define E_EDGES 393216
#define TOT_EDGES (E_EDGES + N_NODES)  // 405504

typedef __attribute__((ext_vector_type(8))) short bf16x8;
typedef __attribute__((ext_vector_type(16))) float f32x16;

__device__ inline unsigned short f2bf_rne(float f) {
  unsigned int u = __float_as_uint(f);
  unsigned int r = u + 0x7fffu + ((u >> 16) & 1u);
  return (unsigned short)(r >> 16);
}
__device__ inline float bf2f(unsigned short h) {
  return __uint_as_float(((unsigned int)h) << 16);
}

// ---------------------------------------------------------------- graph build

__global__ __launch_bounds__(256) void k_init(const float* __restrict__ x,
                                              int* __restrict__ deg,
                                              float* __restrict__ coef) {
  int i = blockIdx.x * 256 + threadIdx.x;
  if (i < N_NODES) {
    deg[i] = 1;  // self loop
    coef[i] = 1.0f - 2.0f * x[(size_t)i * IN_DIM_];
  }
}

__global__ __launch_bounds__(256) void k_count(const int* __restrict__ dst,
                                               int* __restrict__ deg) {
  int e = blockIdx.x * 256 + threadIdx.x;
  if (e < E_EDGES) atomicAdd(&deg[dst[e]], 1);
}

__global__ __launch_bounds__(1024) void k_scan(const int* __restrict__ deg,
                                               int* __restrict__ rowptr,
                                               int* __restrict__ cursor,
                                               float* __restrict__ dinv) {
  __shared__ int sh[1024];
  const int t = threadIdx.x;
  int loc[12];
  int s = 0;
#pragma unroll
  for (int i = 0; i < 12; i++) {
    int d = deg[t * 12 + i];
    dinv[t * 12 + i] = 1.0f / sqrtf((float)d);
    loc[i] = s;
    s += d;
  }
  sh[t] = s;
  __syncthreads();
  for (int off = 1; off < 1024; off <<= 1) {
    int v = (t >= off) ? sh[t - off] : 0;
    __syncthreads();
    sh[t] += v;
    __syncthreads();
  }
  int base = sh[t] - s;  // exclusive
#pragma unroll
  for (int i = 0; i < 12; i++) {
    int v = base + loc[i];
    rowptr[t * 12 + i] = v;
    cursor[t * 12 + i] = v;
  }
  if (t == 1023) rowptr[N_NODES] = sh[1023];
}

__global__ __launch_bounds__(256) void k_fill(const int* __restrict__ src,
                                              const int* __restrict__ dst,
                                              const float* __restrict__ dinv,
                                              int* __restrict__ cursor,
                                              int* __restrict__ col,
                                              float* __restrict__ wgt) {
  int e = blockIdx.x * 256 + threadIdx.x;
  if (e < E_EDGES) {
    int s = src[e], d = dst[e];
    int pos = atomicAdd(&cursor[d], 1);
    col[pos] = s;
    wgt[pos] = dinv[s] * dinv[d];
  } else if (e < TOT_EDGES) {
    int i = e - E_EDGES;
    int pos = atomicAdd(&cursor[i], 1);
    col[pos] = i;
    float di = dinv[i];
    wgt[pos] = di * di;
  }
}

// ---------------------------------------------------------------- enc GEMM 1
// HWe1 = x @ enc_W1 (K=256, chunked LDS, float4 loads)

template <int K, int KC, int NF, int LDW, int RPT>
__global__ __launch_bounds__(256) void k_gemm_v4(const float* __restrict__ A,
                                                 const float* __restrict__ W,
                                                 float* __restrict__ C) {
  __shared__ float Ws[KC * NF];
  constexpr int G = 256 / NF;
  const int c = threadIdx.x % NF;
  const int rg = threadIdx.x / NF;
  const int r0 = blockIdx.x * (G * RPT) + rg * RPT;
  float acc[RPT];
#pragma unroll
  for (int i = 0; i < RPT; i++) acc[i] = 0.0f;
  for (int k0 = 0; k0 < K; k0 += KC) {
    __syncthreads();
    for (int t = threadIdx.x; t < KC * NF; t += 256)
      Ws[t] = W[(k0 + t / NF) * LDW + (t % NF)];
    __syncthreads();
#pragma unroll 2
    for (int k = 0; k < KC; k += 4) {
      float4 a[RPT];
#pragma unroll
      for (int i = 0; i < RPT; i++)
        a[i] = *(const float4*)&A[(size_t)(r0 + i) * K + k0 + k];
      float w0 = Ws[(k + 0) * NF + c];
      float w1 = Ws[(k + 1) * NF + c];
      float w2 = Ws[(k + 2) * NF + c];
      float w3 = Ws[(k + 3) * NF + c];
#pragma unroll
      for (int i = 0; i < RPT; i++) {
        acc[i] = fmaf(a[i].x, w0, acc[i]);
        acc[i] = fmaf(a[i].y, w1, acc[i]);
        acc[i] = fmaf(a[i].z, w2, acc[i]);
        acc[i] = fmaf(a[i].w, w3, acc[i]);
      }
    }
  }
#pragma unroll
  for (int i = 0; i < RPT; i++) C[(size_t)(r0 + i) * NF + c] = acc[i];
}

// ---------------------------------------------------------------- enc fused
// One gather pass over HWe1 produces h1 AND h1cf via rank-1 identity:
//   h1cf_acc = h1_acc + wr[lane] * (sum_e w_e * coef[c_e])
// then applies eW2 in-LDS: HWe2 = h1 @ eW2 (64 cols), t32 = h1cf @ eW2[:, :32].

__global__ __launch_bounds__(256) void k_enc_fused(
    const float* __restrict__ in, const int* __restrict__ rowptr,
    const int* __restrict__ col, const float* __restrict__ wgt,
    const float* __restrict__ b1, const float* __restrict__ coef,
    const float* __restrict__ wrow, const float* __restrict__ eW2,
    float* __restrict__ HWe2, float* __restrict__ t32) {
  __shared__ float Ws[64 * 64];   // 16 KB
  __shared__ float h1s[4][64];
  __shared__ float h1cfs[4][64];
  for (int i = threadIdx.x; i < 64 * 64; i += 256) Ws[i] = eW2[i];

  const int lane = threadIdx.x & 63;
  const int wv = threadIdx.x >> 6;
  int node = __builtin_amdgcn_readfirstlane(blockIdx.x * 4 + wv);
  const int start = rowptr[node];
  const int end = rowptr[node + 1];
  const float wr = wrow[lane];
  float a0 = 0, a1 = 0, a2 = 0, a3 = 0;
  float s0 = 0, s1 = 0, s2 = 0, s3 = 0;
  int e = start;
  for (; e + 8 <= end; e += 8) {
    int c0 = col[e + 0], c1 = col[e + 1], c2 = col[e + 2], c3 = col[e + 3];
    int c4 = col[e + 4], c5 = col[e + 5], c6 = col[e + 6], c7 = col[e + 7];
    float w0 = wgt[e + 0], w1 = wgt[e + 1], w2 = wgt[e + 2], w3 = wgt[e + 3];
    float w4 = wgt[e + 4], w5 = wgt[e + 5], w6 = wgt[e + 6], w7 = wgt[e + 7];
    float v0 = in[(size_t)c0 * 64 + lane];
    float v1 = in[(size_t)c1 * 64 + lane];
    float v2 = in[(size_t)c2 * 64 + lane];
    float v3 = in[(size_t)c3 * 64 + lane];
    float v4 = in[(size_t)c4 * 64 + lane];
    float v5 = in[(size_t)c5 * 64 + lane];
    float v6 = in[(size_t)c6 * 64 + lane];
    float v7 = in[(size_t)c7 * 64 + lane];
    a0 = fmaf(w0, v0, a0);
    a1 = fmaf(w1, v1, a1);
    a2 = fmaf(w2, v2, a2);
    a3 = fmaf(w3, v3, a3);
    a0 = fmaf(w4, v4, a0);
    a1 = fmaf(w5, v5, a1);
    a2 = fmaf(w6, v6, a2);
    a3 = fmaf(w7, v7, a3);
    s0 = fmaf(w0, coef[c0], s0);
    s1 = fmaf(w1, coef[c1], s1);
    s2 = fmaf(w2, coef[c2], s2);
    s3 = fmaf(w3, coef[c3], s3);
    s0 = fmaf(w4, coef[c4], s0);
    s1 = fmaf(w5, coef[c5], s1);
    s2 = fmaf(w6, coef[c6], s2);
    s3 = fmaf(w7, coef[c7], s3);
  }
  for (; e < end; ++e) {
    int c = col[e];
    float we = wgt[e];
    a0 = fmaf(we, in[(size_t)c * 64 + lane], a0);
    s0 = fmaf(we, coef[c], s0);
  }
  float acc = (a0 + a1) + (a2 + a3);
  float s = (s0 + s1) + (s2 + s3);
  float bb = b1[lane];
  h1s[wv][lane] = fmaxf(acc + bb, 0.0f);
  h1cfs[wv][lane] = fmaxf(fmaf(wr, s, acc) + bb, 0.0f);
  __syncthreads();  // Ws staged + h rows visible

  // GEMM phase: each thread handles (node = wv, col = lane)
  float A2 = 0, A3 = 0;
#pragma unroll 4
  for (int k = 0; k < 64; ++k) {
    float wv_ = Ws[k * 64 + lane];
    A2 = fmaf(h1s[wv][k], wv_, A2);
    A3 = fmaf(h1cfs[wv][k], wv_, A3);
  }
  size_t n = (size_t)blockIdx.x * 4 + wv;
  HWe2[n * 64 + lane] = A2;
  if (lane < 32) t32[n * 32 + lane] = A3;
}

// ---------------------------------------------------------------- z stage
// y==0: z = A(HWe2)+b2 split into zs/zns; y==1 (x<1536): zscf = A(t32)+b2[:32].

__global__ __launch_bounds__(256) void k_agg_z(
    const float* __restrict__ in64, const float* __restrict__ in32,
    const int* __restrict__ rowptr, const int* __restrict__ col,
    const float* __restrict__ wgt, const float* __restrict__ bias,
    float* __restrict__ out_zs, float* __restrict__ out_zns,
    float* __restrict__ out_zscf) {
  if (blockIdx.y == 0) {
    const int lane = threadIdx.x & 63;
    int node = blockIdx.x * 4 + (threadIdx.x >> 6);
    node = __builtin_amdgcn_readfirstlane(node);
    const int start = rowptr[node];
    const int end = rowptr[node + 1];
    float a0 = 0, a1 = 0, a2 = 0, a3 = 0;
    int e = start;
    for (; e + 8 <= end; e += 8) {
      int c0 = col[e + 0], c1 = col[e + 1], c2 = col[e + 2], c3 = col[e + 3];
      int c4 = col[e + 4], c5 = col[e + 5], c6 = col[e + 6], c7 = col[e + 7];
      float w0 = wgt[e + 0], w1 = wgt[e + 1], w2 = wgt[e + 2], w3 = wgt[e + 3];
      float w4 = wgt[e + 4], w5 = wgt[e + 5], w6 = wgt[e + 6], w7 = wgt[e + 7];
      float v0 = in64[(size_t)c0 * 64 + lane];
      float v1 = in64[(size_t)c1 * 64 + lane];
      float v2 = in64[(size_t)c2 * 64 + lane];
      float v3 = in64[(size_t)c3 * 64 + lane];
      float v4 = in64[(size_t)c4 * 64 + lane];
      float v5 = in64[(size_t)c5 * 64 + lane];
      float v6 = in64[(size_t)c6 * 64 + lane];
      float v7 = in64[(size_t)c7 * 64 + lane];
      a0 = fmaf(w0, v0, a0);
      a1 = fmaf(w1, v1, a1);
      a2 = fmaf(w2, v2, a2);
      a3 = fmaf(w3, v3, a3);
      a0 = fmaf(w4, v4, a0);
      a1 = fmaf(w5, v5, a1);
      a2 = fmaf(w6, v6, a2);
      a3 = fmaf(w7, v7, a3);
    }
    for (; e < end; ++e) {
      int c = col[e];
      a0 = fmaf(wgt[e], in64[(size_t)c * 64 + lane], a0);
    }
    float acc = (a0 + a1) + (a2 + a3) + bias[lane];
    if (lane < 32)
      out_zs[(size_t)node * 32 + lane] = acc;
    else
      out_zns[(size_t)node * 32 + (lane - 32)] = acc;
  } else {
    if (blockIdx.x >= 1536) return;
    const int lane = threadIdx.x & 31;
    const int node = blockIdx.x * 8 + (threadIdx.x >> 5);
    const int start = rowptr[node];
    const int end = rowptr[node + 1];
    float a0 = 0, a1 = 0, a2 = 0, a3 = 0;
    int e = start;
    for (; e + 8 <= end; e += 8) {
      int c0 = col[e + 0], c1 = col[e + 1], c2 = col[e + 2], c3 = col[e + 3];
      int c4 = col[e + 4], c5 = col[e + 5], c6 = col[e + 6], c7 = col[e + 7];
      float w0 = wgt[e + 0], w1 = wgt[e + 1], w2 = wgt[e + 2], w3 = wgt[e + 3];
      float w4 = wgt[e + 4], w5 = wgt[e + 5], w6 = wgt[e + 6], w7 = wgt[e + 7];
      a0 = fmaf(w0, in32[(size_t)c0 * 32 + lane], a0);
      a1 = fmaf(w1, in32[(size_t)c1 * 32 + lane], a1);
      a2 = fmaf(w2, in32[(size_t)c2 * 32 + lane], a2);
      a3 = fmaf(w3, in32[(size_t)c3 * 32 + lane], a3);
      a0 = fmaf(w4, in32[(size_t)c4 * 32 + lane], a0);
      a1 = fmaf(w5, in32[(size_t)c5 * 32 + lane], a1);
      a2 = fmaf(w6, in32[(size_t)c6 * 32 + lane], a2);
      a3 = fmaf(w7, in32[(size_t)c7 * 32 + lane], a3);
    }
    for (; e < end; ++e)
      a0 = fmaf(wgt[e], in32[(size_t)col[e] * 32 + lane], a0);
    out_zscf[(size_t)node * 32 + lane] = (a0 + a1) + (a2 + a3) + bias[lane];
  }
}

// ---------------------------------------------------------------- u fused
// y=0: u1 = relu(A(zs)@d1W1+b); y=1: u1cf = relu(A(zscf)@d1W1+b);
// y=2: u2 = relu(A(zns)@d2W1+b) AND hs = A(zns)@sW+sb -> bf16 hi/lo.
// Gather: 32-wide rows, 2 edges/step via half-wave split, shfl_xor combine.

__global__ __launch_bounds__(256) void k_u_fused(
    const float* __restrict__ in0, const float* __restrict__ in1,
    const float* __restrict__ in2, const int* __restrict__ rowptr,
    const int* __restrict__ col, const float* __restrict__ wgt,
    const float* __restrict__ W01, const float* __restrict__ W2,
    const float* __restrict__ Wh, const float* __restrict__ b01,
    const float* __restrict__ b2, const float* __restrict__ bh,
    float* __restrict__ o0, float* __restrict__ o1, float* __restrict__ o2,
    unsigned short* __restrict__ hhi, unsigned short* __restrict__ hlo) {
  __shared__ float Ws[32 * 64];   // 8 KB
  __shared__ float Ws2[32 * 64];  // 8 KB (only used when y==2)
  __shared__ float gsh[4][32];
  const int y = blockIdx.y;
  const float* __restrict__ in = y == 0 ? in0 : (y == 1 ? in1 : in2);
  const float* __restrict__ W = y == 2 ? W2 : W01;
  const float* __restrict__ bias = y == 2 ? b2 : b01;
  for (int i = threadIdx.x; i < 32 * 64; i += 256) Ws[i] = W[i];
  if (y == 2)
    for (int i = threadIdx.x; i < 32 * 64; i += 256) Ws2[i] = Wh[i];

  const int lane = threadIdx.x & 63;
  const int wv = threadIdx.x >> 6;
  const int feat = lane & 31;
  const int half = lane >> 5;
  int node = __builtin_amdgcn_readfirstlane(blockIdx.x * 4 + wv);
  const int start = rowptr[node];
  const int end = rowptr[node + 1];
  float a0 = 0, a1 = 0, a2 = 0, a3 = 0;
  int e = start;
  for (; e + 8 <= end; e += 8) {
    int c0 = col[e + 0 + half], c1 = col[e + 2 + half];
    int c2 = col[e + 4 + half], c3 = col[e + 6 + half];
    float w0 = wgt[e + 0 + half], w1 = wgt[e + 2 + half];
    float w2 = wgt[e + 4 + half], w3 = wgt[e + 6 + half];
    a0 = fmaf(w0, in[(size_t)c0 * 32 + feat], a0);
    a1 = fmaf(w1, in[(size_t)c1 * 32 + feat], a1);
    a2 = fmaf(w2, in[(size_t)c2 * 32 + feat], a2);
    a3 = fmaf(w3, in[(size_t)c3 * 32 + feat], a3);
  }
  for (; e + 2 <= end; e += 2) {
    int c = col[e + half];
    a0 = fmaf(wgt[e + half], in[(size_t)c * 32 + feat], a0);
  }
  if (e < end && half == 0) {
    int c = col[e];
    a0 = fmaf(wgt[e], in[(size_t)c * 32 + feat], a0);
  }
  float tot = (a0 + a1) + (a2 + a3);
  tot += __shfl_xor(tot, 32);
  if (half == 0) gsh[wv][feat] = tot;
  __syncthreads();  // Ws staged + g rows visible

  // GEMM phase: node = wv, col = lane
  float A = 0, B = 0;
#pragma unroll 4
  for (int k = 0; k < 32; ++k) {
    float g = gsh[wv][k];
    A = fmaf(g, Ws[k * 64 + lane], A);
    if (y == 2) B = fmaf(g, Ws2[k * 64 + lane], B);
  }
  size_t n = (size_t)blockIdx.x * 4 + wv;
  float* __restrict__ o = y == 0 ? o0 : (y == 1 ? o1 : o2);
  o[n * 64 + lane] = fmaxf(A + bias[lane], 0.0f);
  if (y == 2) {
    float v = B + bh[lane];
    unsigned short h = f2bf_rne(v);
    float l = v - bf2f(h);
    hhi[n * 64 + lane] = h;
    hlo[n * 64 + lane] = f2bf_rne(l);
  }
}

// ---------------------------------------------------------------- dec fused
// y slice: x_hat = A(u) @ W(64x256) + b, gather + chunked-LDS GEMM in one pass.

__global__ __launch_bounds__(256) void k_dec_fused(
    const float* __restrict__ in0, const float* __restrict__ in1,
    const float* __restrict__ in2, const int* __restrict__ rowptr,
    const int* __restrict__ col, const float* __restrict__ wgt,
    const float* __restrict__ W01, const float* __restrict__ W2,
    const float* __restrict__ b01, const float* __restrict__ b2,
    float* __restrict__ o0, float* __restrict__ o1, float* __restrict__ o2) {
  __shared__ float Wc[16 * 256];  // 16 KB chunk
  __shared__ float gsh[4][64];
  const int y = blockIdx.y;
  const float* __restrict__ in = y == 0 ? in0 : (y == 1 ? in1 : in2);
  const float* __restrict__ W = y == 2 ? W2 : W01;
  const float* __restrict__ bias = y == 2 ? b2 : b01;
  float* __restrict__ o = y == 0 ? o0 : (y == 1 ? o1 : o2);

  const int lane = threadIdx.x & 63;
  const int wv = threadIdx.x >> 6;
  int node = __builtin_amdgcn_readfirstlane(blockIdx.x * 4 + wv);
  const int start = rowptr[node];
  const int end = rowptr[node + 1];
  float a0 = 0, a1 = 0, a2 = 0, a3 = 0;
  int e = start;
  for (; e + 8 <= end; e += 8) {
    int c0 = col[e + 0], c1 = col[e + 1], c2 = col[e + 2], c3 = col[e + 3];
    int c4 = col[e + 4], c5 = col[e + 5], c6 = col[e + 6], c7 = col[e + 7];
    float w0 = wgt[e + 0], w1 = wgt[e + 1], w2 = wgt[e + 2], w3 = wgt[e + 3];
    float w4 = wgt[e + 4], w5 = wgt[e + 5], w6 = wgt[e + 6], w7 = wgt[e + 7];
    float v0 = in[(size_t)c0 * 64 + lane];
    float v1 = in[(size_t)c1 * 64 + lane];
    float v2 = in[(size_t)c2 * 64 + lane];
    float v3 = in[(size_t)c3 * 64 + lane];
    float v4 = in[(size_t)c4 * 64 + lane];
    float v5 = in[(size_t)c5 * 64 + lane];
    float v6 = in[(size_t)c6 * 64 + lane];
    float v7 = in[(size_t)c7 * 64 + lane];
    a0 = fmaf(w0, v0, a0);
    a1 = fmaf(w1, v1, a1);
    a2 = fmaf(w2, v2, a2);
    a3 = fmaf(w3, v3, a3);
    a0 = fmaf(w4, v4, a0);
    a1 = fmaf(w5, v5, a1);
    a2 = fmaf(w6, v6, a2);
    a3 = fmaf(w7, v7, a3);
  }
  for (; e < end; ++e) {
    int c = col[e];
    a0 = fmaf(wgt[e], in[(size_t)c * 64 + lane], a0);
  }
  gsh[wv][lane] = (a0 + a1) + (a2 + a3);

  // chunked GEMM: thread computes (node = wv) cols lane, lane+64, +128, +192
  float acc[4] = {0, 0, 0, 0};
  for (int k0 = 0; k0 < 64; k0 += 16) {
    __syncthreads();  // protect Wc from previous chunk's readers
    for (int t = threadIdx.x; t < 16 * 256; t += 256)
      Wc[t] = W[(k0 + (t >> 8)) * 256 + (t & 255)];
    __syncthreads();
#pragma unroll 4
    for (int k = 0; k < 16; ++k) {
      float g = gsh[wv][k0 + k];
      acc[0] = fmaf(g, Wc[k * 256 + lane], acc[0]);
      acc[1] = fmaf(g, Wc[k * 256 + lane + 64], acc[1]);
      acc[2] = fmaf(g, Wc[k * 256 + lane + 128], acc[2]);
      acc[3] = fmaf(g, Wc[k * 256 + lane + 192], acc[3]);
    }
  }
  size_t base = ((size_t)blockIdx.x * 4 + wv) * 256;
  o[base + lane] = acc[0] + bias[lane];
  o[base + lane + 64] = acc[1] + bias[lane + 64];
  o[base + lane + 128] = acc[2] + bias[lane + 128];
  o[base + lane + 192] = acc[3] + bias[lane + 192];
}

// ---------------------------------------------------------------- s_ = hs@hs^T
// bf16 MFMA (32x32x16), hi/lo split: hi*hi + hi*lo + lo*hi ~ fp32 accuracy.

__global__ __launch_bounds__(256) void k_syrk_mfma(
    const unsigned short* __restrict__ hhi, const unsigned short* __restrict__ hlo,
    float* __restrict__ out) {
  const int tid = threadIdx.x;
  const int lane = tid & 63;
  const int wave = tid >> 6;
  const int wy = wave >> 1, wx = wave & 1;
  const int m = lane & 31;
  const int koff = (lane >> 5) * 8;
  const size_t rb = (size_t)blockIdx.y * 128 + wy * 64;
  const size_t cb = (size_t)blockIdx.x * 128 + wx * 64;
  f32x16 acc[2][2];
#pragma unroll
  for (int i = 0; i < 2; i++)
#pragma unroll
    for (int j = 0; j < 2; j++) acc[i][j] = (f32x16)(0.0f);
#pragma unroll
  for (int k0 = 0; k0 < 64; k0 += 16) {
    bf16x8 ah[2], al[2], bh[2], bl[2];
#pragma unroll
    for (int t = 0; t < 2; t++) {
      size_t ra = (rb + t * 32 + m) * 64 + k0 + koff;
      ah[t] = *(const bf16x8*)(hhi + ra);
      al[t] = *(const bf16x8*)(hlo + ra);
      size_t rc = (cb + t * 32 + m) * 64 + k0 + koff;
      bh[t] = *(const bf16x8*)(hhi + rc);
      bl[t] = *(const bf16x8*)(hlo + rc);
    }
#pragma unroll
    for (int i = 0; i < 2; i++)
#pragma unroll
      for (int j = 0; j < 2; j++) {
        acc[i][j] = __builtin_amdgcn_mfma_f32_32x32x16_bf16(ah[i], bh[j], acc[i][j], 0, 0, 0);
        acc[i][j] = __builtin_amdgcn_mfma_f32_32x32x16_bf16(ah[i], bl[j], acc[i][j], 0, 0, 0);
        acc[i][j] = __builtin_amdgcn_mfma_f32_32x32x16_bf16(al[i], bh[j], acc[i][j], 0, 0, 0);
      }
  }
  // C/D layout (32x32): col = lane&31, row = (r&3) + 8*(r>>2) + 4*(lane>>5)
  const int rowoff = 4 * (lane >> 5);
  const int colc = lane & 31;
#pragma unroll
  for (int i = 0; i < 2; i++)
#pragma unroll
    for (int j = 0; j < 2; j++)
#pragma unroll
      for (int r = 0; r < 16; r++) {
        size_t row = rb + i * 32 + (r & 3) + 8 * (r >> 2) + rowoff;
        out[row * 12288 + cb + j * 32 + colc] = acc[i][j][r];
      }
}

// ---------------------------------------------------------------- launch

extern "C" void kernel_launch(void* const* d_in, const int* in_sizes, int n_in,
                              void* d_out, int out_size, void* d_ws,
                              size_t ws_size, hipStream_t stream) {
  (void)in_sizes; (void)n_in; (void)out_size; (void)ws_size;
  const float* x = (const float*)d_in[0];
  const int* ei = (const int*)d_in[1];
  const int* src = ei;
  const int* dst = ei + E_EDGES;
  const float* eW1 = (const float*)d_in[2];
  const float* eb1 = (const float*)d_in[3];
  const float* eW2 = (const float*)d_in[4];
  const float* eb2 = (const float*)d_in[5];
  const float* d1W1 = (const float*)d_in[6];
  const float* d1b1 = (const float*)d_in[7];
  const float* d1W2 = (const float*)d_in[8];
  const float* d1b2 = (const float*)d_in[9];
  const float* d2W1 = (const float*)d_in[10];
  const float* d2b1 = (const float*)d_in[11];
  const float* d2W2 = (const float*)d_in[12];
  const float* d2b2 = (const float*)d_in[13];
  const float* sW = (const float*)d_in[14];
  const float* sb = (const float*)d_in[15];

  float* out = (float*)d_out;
  float* out_zs = out;                  // 12288 x 32
  float* out_zns = out + 393216;        // 12288 x 32
  float* out_xs = out + 786432;         // 12288 x 256
  float* out_xns = out + 3932160;       // 12288 x 256
  float* out_xscf = out + 7077888;      // 12288 x 256
  float* out_s = out + 10223616;        // 12288 x 12288

  char* w = (char*)d_ws;
  size_t o = 0;
  auto alloc = [&](size_t bytes) -> void* {
    void* p = (void*)(w + o);
    o += (bytes + 255) & ~(size_t)255;
    return p;
  };
  int* deg = (int*)alloc(N_NODES * 4);
  int* rowptr = (int*)alloc((N_NODES + 1) * 4);
  int* cursor = (int*)alloc(N_NODES * 4);
  int* col = (int*)alloc(TOT_EDGES * 4);
  float* wgt = (float*)alloc(TOT_EDGES * 4);
  float* dinv = (float*)alloc(N_NODES * 4);
  float* coef = (float*)alloc(N_NODES * 4);
  const size_t B64 = (size_t)N_NODES * 64 * 4;
  const size_t B32 = (size_t)N_NODES * 32 * 4;
  float* slotA = (float*)alloc(B64);  // HWe1 -> u1
  float* slotB = (float*)alloc(B64);  // HWe2
  float* slotC = (float*)alloc(B64);  // u1cf
  float* slotU3 = (float*)alloc(B64); // u2
  float* t32 = (float*)alloc(B32);
  float* zscf = (float*)alloc(B32);
  unsigned short* hhi = (unsigned short*)alloc((size_t)N_NODES * 64 * 2);
  unsigned short* hlo = (unsigned short*)alloc((size_t)N_NODES * 64 * 2);

  // ---- graph build (4)
  k_init<<<48, 256, 0, stream>>>(x, deg, coef);
  k_count<<<1536, 256, 0, stream>>>(dst, deg);
  k_scan<<<1, 1024, 0, stream>>>(deg, rowptr, cursor, dinv);
  k_fill<<<1584, 256, 0, stream>>>(src, dst, dinv, cursor, col, wgt);

  // ---- encoder (3)
  // HWe1 = x @ enc_W1
  k_gemm_v4<256, 64, 64, 64, 4><<<768, 256, 0, stream>>>(x, eW1, slotA);
  // fused: h1/h1cf gather (rank-1 single pass) + @eW2 -> HWe2, t32
  k_enc_fused<<<3072, 256, 0, stream>>>(slotA, rowptr, col, wgt, eb1, coef,
                                        eW1, eW2, slotB, t32);
  // z = A(HWe2)+b2 -> zs/zns ; zscf = A(t32)+b2[:32]
  k_agg_z<<<dim3(3072, 2), 256, 0, stream>>>(slotB, t32, rowptr, col, wgt,
                                             eb2, out_zs, out_zns, zscf);

  // ---- decoder fused stages (2)
  // u1/u1cf/u2 (+hs bf16) = relu(A(z*)@W1+b) fused gather+GEMM
  k_u_fused<<<dim3(3072, 3), 256, 0, stream>>>(
      out_zs, zscf, out_zns, rowptr, col, wgt, d1W1, d2W1, sW, d1b1, d2b1, sb,
      slotA, slotC, slotU3, hhi, hlo);
  // x_s_hat / x_s_cf_hat / x_ns_hat = A(u*)@W2+b fused gather+GEMM
  k_dec_fused<<<dim3(3072, 3), 256, 0, stream>>>(
      slotA, slotC, slotU3, rowptr, col, wgt, d1W2, d2W2, d1b2, d2b2, out_xs,
      out_xscf, out_xns);

  // ---- s_ = hs @ hs^T  (bf16 MFMA, hi/lo corrected) (1)
  k_syrk_mfma<<<dim3(96, 96), 256, 0, stream>>>(hhi, hlo, out_s);
}